// Round 4
// baseline (175.593 us; speedup 1.0000x reference)
//
#include <hip/hip_runtime.h>

// ---- problem constants --------------------------------------------------
#define B_ 4
#define L_ 4096
#define D_ 256
#define M_ 512
#define C_ 256
#define NC_ 16
#define NG_ (B_*NC_)
#define EPS_ 1e-6f
#define RSQRT_D_ 0.0625f
#define RSQRT_M_ 0.044194173824159216f

typedef __attribute__((ext_vector_type(8))) short short8;
typedef __attribute__((ext_vector_type(4))) short short4v;
typedef __attribute__((ext_vector_type(4))) float floatx4;

// ---- bf16 helpers (RNE) -------------------------------------------------
__device__ __forceinline__ short f2b(float f) {
  union { float f; unsigned u; } c; c.f = f;
  unsigned r = c.u + 0x7fffu + ((c.u >> 16) & 1u);
  return (short)(r >> 16);
}
__device__ __forceinline__ float b2f(short s) {
  union { unsigned u; float f; } c; c.u = ((unsigned)(unsigned short)s) << 16;
  return c.f;
}

// async global->LDS, 16B per lane. LDS dest must be wave-uniform base +
// lane*16 (linear); swizzle is applied on the GLOBAL source side (m173).
__device__ __forceinline__ void async_copy16(const short* g, short* l) {
  __builtin_amdgcn_global_load_lds(
      (const __attribute__((address_space(1))) void*)(g),
      (__attribute__((address_space(3))) void*)(l), 16, 0, 0);
}

// ---- workspace layout (byte offsets) ------------------------------------
#define OFF_SB   0u
#define OFF_WT   16777216u
#define OFF_QP   17039360u
#define OFF_KP   33816576u
#define OFF_KPT  50593792u
#define OFF_VT   67371008u
#define OFF_AM   75759616u
#define OFF_PB   84148224u
#define OFF_ZP   100925440u

// ======================================================================
// MFMA GEMM core, round-3: global_load_lds staging (linear LDS dest,
// inverse-swizzled global source). C[128x128] += A[128xK]*B[128xK]^T.
// dst(m,k8) = (k8>>2)*512 + (m>>4)*64 + (k8&3)*16 + ((m&15)^k8)
// inverse: x=s&15, l=(s>>4)&3, M=(s>>6)&7, h=s>>9; k8=4h+l; m=16M+(x^k8)
// ======================================================================
__device__ __forceinline__ void mfma_tile_gemm(
    const short* __restrict__ Ag, int lda,
    const short* __restrict__ Bg, int ldb,
    int K, short* sA, short* sB, floatx4 acc[4][4])
{
  const int tid  = threadIdx.x;
  const int lane = tid & 63;
  const int wave = tid >> 6;
  const int wm = wave >> 1, wn = wave & 1;
  const int q = lane >> 4, ml = lane & 15;

  int mloc[4], koff[4];
  #pragma unroll
  for (int it = 0; it < 4; ++it) {
    int s = tid + 256 * it;
    int x = s & 15, l = (s >> 4) & 3, M = (s >> 6) & 7, h = s >> 9;
    int k8 = 4 * h + l;
    mloc[it] = M * 16 + (x ^ k8);
    koff[it] = k8 * 8;
  }
  for (int k0 = 0; k0 < K; k0 += 64) {
    #pragma unroll
    for (int it = 0; it < 4; ++it) {
      int s = tid + 256 * it;
      async_copy16(Ag + (size_t)mloc[it] * lda + k0 + koff[it], sA + s * 8);
      async_copy16(Bg + (size_t)mloc[it] * ldb + k0 + koff[it], sB + s * 8);
    }
    __syncthreads();   // compiler drains vmcnt(0) before s_barrier
    #pragma unroll
    for (int ks = 0; ks < 2; ++ks) {
      short8 a[4], b[4];
      int k8 = ks * 4 + q;
      #pragma unroll
      for (int i = 0; i < 4; ++i) {
        int ca = ks * 512 + (wm * 4 + i) * 64 + q * 16 + (ml ^ k8);
        a[i] = *(const short8*)(sA + ca * 8);
        int cb = ks * 512 + (wn * 4 + i) * 64 + q * 16 + (ml ^ k8);
        b[i] = *(const short8*)(sB + cb * 8);
      }
      #pragma unroll
      for (int i = 0; i < 4; ++i)
        #pragma unroll
        for (int j = 0; j < 4; ++j)
          acc[i][j] = __builtin_amdgcn_mfma_f32_16x16x32_bf16(a[i], b[j], acc[i][j], 0, 0, 0);
    }
    __syncthreads();
  }
}

// ---- K1: combined transpose+cvt: v (z<NG_) and W (z==NG_) ---------------
__global__ __launch_bounds__(256) void transpose_cvt_kernel(
    const float* __restrict__ v, const float* __restrict__ W,
    short* __restrict__ vT, short* __restrict__ Wt)
{
  const int z = blockIdx.z;
  const float* src; short* dst; int ld_in, ld_out;
  if (z < NG_) {
    if (blockIdx.x >= 4) return;
    src = v + (size_t)z * (C_*D_) + (size_t)blockIdx.y * 64 * D_ + blockIdx.x * 64;
    dst = vT + (size_t)z * (D_*C_) + (size_t)blockIdx.x * 64 * C_ + blockIdx.y * 64;
    ld_in = D_; ld_out = C_;
  } else {
    src = W + (size_t)blockIdx.y * 64 * M_ + blockIdx.x * 64;
    dst = Wt + (size_t)blockIdx.x * 64 * D_ + blockIdx.y * 64;
    ld_in = M_; ld_out = D_;
  }
  __shared__ short sm[64 * 65];
  const int tid = threadIdx.x;
  #pragma unroll
  for (int it = 0; it < 4; ++it) {
    int ci = tid + 256 * it;
    int row = ci >> 4, c4 = ci & 15;
    float4 x = *(const float4*)(src + (size_t)row * ld_in + c4 * 4);
    sm[(c4 * 4 + 0) * 65 + row] = f2b(x.x);
    sm[(c4 * 4 + 1) * 65 + row] = f2b(x.y);
    sm[(c4 * 4 + 2) * 65 + row] = f2b(x.z);
    sm[(c4 * 4 + 3) * 65 + row] = f2b(x.w);
  }
  __syncthreads();
  #pragma unroll
  for (int it = 0; it < 2; ++it) {
    int ci = tid + 256 * it;
    int dr = ci >> 3, t8 = ci & 7;
    short8 o;
    #pragma unroll
    for (int u = 0; u < 8; ++u) o[u] = sm[dr * 65 + t8 * 8 + u];
    *(short8*)(dst + (size_t)dr * ld_out + t8 * 8) = o;
  }
}

// ---- K2: merged q/k phi = exp(X@W/sqrt(d) - 0.5||x||^2)/sqrt(M) ---------
// 128 rows x 256 cols, 512 threads (8 waves 2x4).
// Round-3: Wt operand staged via global_load_lds (pure bf16 copy);
// X operand keeps reg path (fp32->bf16 conversion + ssq need VGPRs).
__global__ __launch_bounds__(512) void phi_mfma_kernel(
    const float* __restrict__ qin, const float* __restrict__ kin,
    const short* __restrict__ Wt,
    short* __restrict__ qp, short* __restrict__ kp, short* __restrict__ kpT,
    float* __restrict__ ZP)
{
  const bool is_k = (blockIdx.z == 1);
  const float* X = is_k ? kin : qin;
  short* outP = is_k ? kp : qp;
  // XCD-affine: the 2 col-tiles sharing X rows get the same (id mod 8).
  const int idl = blockIdx.x + 2 * blockIdx.y;          // [0,256)
  const int row0 = ((idl & 7) + 8 * (idl >> 4)) * 128;  // [0,16384)
  const int col0 = ((idl >> 3) & 1) * 256;              // {0,256}
  __shared__ short smem[34816];
  __shared__ float zsb[512];
  __shared__ float sqs[128];
  short* sA = smem;
  short* sB = smem + 8192;
  const int tid = threadIdx.x, lane = tid & 63, wave = tid >> 6;
  const int wm = wave >> 2, wn = wave & 3, q = lane >> 4, ml = lane & 15;
  const int c8 = tid & 7, r8 = tid >> 3;   // r8 in [0,64)
  floatx4 acc[4][4];
  #pragma unroll
  for (int i = 0; i < 4; ++i)
    #pragma unroll
    for (int j = 0; j < 4; ++j) acc[i][j] = (floatx4){0.f,0.f,0.f,0.f};

  // Wt source decode: sB unit s = c8*256 + (mm^c8)  ->  c8=s>>8, mm=(s&255)^c8
  int wmm[4], wc8[4];
  #pragma unroll
  for (int it = 0; it < 4; ++it) {
    int s = tid + 512 * it;
    int cc = s >> 8;
    wmm[it] = (s & 255) ^ cc;
    wc8[it] = cc;
  }

  // X prefetch: thread covers rows r8 and r8+64, k-cols [c8*8, c8*8+8)
  float4 px0[2], px1[2];
  #pragma unroll
  for (int it = 0; it < 2; ++it) {
    const float* src = X + (size_t)(row0 + r8 + 64 * it) * D_ + c8 * 8;
    px0[it] = *(const float4*)src;
    px1[it] = *(const float4*)(src + 4);
  }
  float ssq[2] = {0.f, 0.f};
  for (int k0 = 0; k0 < D_; k0 += 64) {
    // stage Wt via async copy (L2-resident, no VGPR round-trip)
    #pragma unroll
    for (int it = 0; it < 4; ++it) {
      int s = tid + 512 * it;
      async_copy16(Wt + (size_t)(col0 + wmm[it]) * D_ + k0 + wc8[it] * 8, sB + s * 8);
    }
    // stage X (f2b + ssq) into sA: 128 rows x 64
    #pragma unroll
    for (int it = 0; it < 2; ++it) {
      int m = r8 + 64 * it;
      float4 x0 = px0[it], x1 = px1[it];
      short8 vv;
      vv[0] = f2b(x0.x); vv[1] = f2b(x0.y); vv[2] = f2b(x0.z); vv[3] = f2b(x0.w);
      vv[4] = f2b(x1.x); vv[5] = f2b(x1.y); vv[6] = f2b(x1.z); vv[7] = f2b(x1.w);
      ssq[it] += x0.x*x0.x + x0.y*x0.y + x0.z*x0.z + x0.w*x0.w
               + x1.x*x1.x + x1.y*x1.y + x1.z*x1.z + x1.w*x1.w;
      *(short8*)(sA + (c8 * 128 + (m ^ c8)) * 8) = vv;
    }
    if (k0 + 64 < D_) {     // prefetch next X slice before the barrier
      #pragma unroll
      for (int it = 0; it < 2; ++it) {
        const float* src = X + (size_t)(row0 + r8 + 64 * it) * D_ + k0 + 64 + c8 * 8;
        px0[it] = *(const float4*)src;
        px1[it] = *(const float4*)(src + 4);
      }
    }
    __syncthreads();
    #pragma unroll
    for (int ks = 0; ks < 2; ++ks) {
      short8 a[4], b[4];
      int kk = ks * 4 + q;
      #pragma unroll
      for (int i = 0; i < 4; ++i) {
        int ra = (wm * 64 + i * 16 + ml) ^ kk;
        a[i] = *(const short8*)(sA + (kk * 128 + ra) * 8);
        int rb = (wn * 64 + i * 16 + ml) ^ kk;
        b[i] = *(const short8*)(sB + (kk * 256 + rb) * 8);
      }
      #pragma unroll
      for (int i = 0; i < 4; ++i)
        #pragma unroll
        for (int j = 0; j < 4; ++j)
          acc[i][j] = __builtin_amdgcn_mfma_f32_16x16x32_bf16(a[i], b[j], acc[i][j], 0, 0, 0);
    }
    __syncthreads();
  }
  // reduce ssq across the 8 threads sharing r8 (consecutive lanes)
  #pragma unroll
  for (int o = 1; o < 8; o <<= 1)
    #pragma unroll
    for (int it = 0; it < 2; ++it) ssq[it] += __shfl_xor(ssq[it], o);
  if (c8 == 0) {
    sqs[r8] = 0.5f * ssq[0];
    sqs[r8 + 64] = 0.5f * ssq[1];
  }
  __syncthreads();

  if (!is_k) {
    // ---- q epilogue: exp -> row-major LDS [128][264] -> short8 stores ----
    #pragma unroll
    for (int i = 0; i < 4; ++i) {
      int rl = wm * 64 + i * 16 + q * 4;
      float sqv[4];
      #pragma unroll
      for (int r = 0; r < 4; ++r) sqv[r] = sqs[rl + r];
      #pragma unroll
      for (int j = 0; j < 4; ++j) {
        int cl = wn * 64 + j * 16 + ml;   // [0,256)
        #pragma unroll
        for (int r = 0; r < 4; ++r) {
          float pv = __expf(fmaf(acc[i][j][r], RSQRT_D_, -sqv[r])) * RSQRT_M_;
          smem[(size_t)(rl + r) * 264 + cl] = f2b(pv);
        }
      }
    }
    __syncthreads();
    #pragma unroll
    for (int it = 0; it < 8; ++it) {
      int idx = tid + 512 * it;          // [0,4096)
      int row = idx >> 5, cc8 = idx & 31;
      short8 vv = *(const short8*)(smem + (size_t)row * 264 + cc8 * 8);
      *(short8*)(outP + (size_t)(row0 + row) * M_ + col0 + cc8 * 8) = vv;
    }
  } else {
    // ---- k epilogue: kp store + transpose buffer + zsum ----
    float csum[4] = {0.f, 0.f, 0.f, 0.f};
    #pragma unroll
    for (int i = 0; i < 4; ++i) {
      int rl = wm * 64 + i * 16 + q * 4;
      float sqv[4];
      #pragma unroll
      for (int r = 0; r < 4; ++r) sqv[r] = sqs[rl + r];
      #pragma unroll
      for (int j = 0; j < 4; ++j) {
        int cl = wn * 64 + j * 16 + ml;   // [0,256)
        short4v tb;
        #pragma unroll
        for (int r = 0; r < 4; ++r) {
          float pv = __expf(fmaf(acc[i][j][r], RSQRT_D_, -sqv[r])) * RSQRT_M_;
          short bv = f2b(pv);
          outP[(size_t)(row0 + rl + r) * M_ + col0 + cl] = bv;
          tb[r] = bv;
          csum[j] += b2f(bv);   // matches old zsum: sums the ROUNDED kp
        }
        *(short4v*)(smem + (size_t)cl * 136 + rl) = tb;
      }
    }
    // column sums: reduce over q (lanes ml, ml+16, ml+32, ml+48)
    #pragma unroll
    for (int j = 0; j < 4; ++j) {
      csum[j] += __shfl_xor(csum[j], 16);
      csum[j] += __shfl_xor(csum[j], 32);
    }
    if (lane < 16) {
      #pragma unroll
      for (int j = 0; j < 4; ++j)
        zsb[wm * 256 + wn * 64 + j * 16 + ml] = csum[j];
    }
    __syncthreads();
    int g = row0 >> 8, tb0 = row0 & 255;
    #pragma unroll
    for (int it = 0; it < 8; ++it) {
      int ci = tid + 512 * it;          // [0,4096)
      int t8 = ci & 15, cc = ci >> 4;   // cc in [0,256)
      short8 vv = *(const short8*)(smem + (size_t)cc * 136 + t8 * 8);
      *(short8*)(kpT + (size_t)g * (M_*C_) + (size_t)(col0 + cc) * C_ + tb0 + t8 * 8) = vv;
    }
    if (tid < 256) {
      float s = zsb[tid] + zsb[256 + tid];
      int p = (row0 >> 7) & 1;
      ZP[((size_t)g * 2 + p) * M_ + col0 + tid] = s;
    }
  }
}

// ---- K3: mega kernel: chunkstate (by<2) + qk (by==2) --------------------
__global__ __launch_bounds__(256) void mega_kernel(
    const short* __restrict__ vT, const short* __restrict__ kpT,
    const short* __restrict__ qp, const short* __restrict__ kp,
    short* __restrict__ Sb, short* __restrict__ Am)
{
  const int id = blockIdx.x + 4 * blockIdx.y + 12 * blockIdx.z;
  const int t12 = id >> 3;
  const int g  = (id & 7) + 8 * (t12 / 12);
  const int inner = t12 % 12;
  const int bx = inner & 3, by = inner >> 2;
  __shared__ short smem[17408];   // gemm uses 16K shorts; epi uses 128x136
  const int tid = threadIdx.x;

  floatx4 acc[4][4];
  #pragma unroll
  for (int i = 0; i < 4; ++i)
    #pragma unroll
    for (int j = 0; j < 4; ++j) acc[i][j] = (floatx4){0.f,0.f,0.f,0.f};
  const int lane = tid & 63, wave = tid >> 6;
  const int wm = wave >> 1, wn = wave & 1, q = lane >> 4, ln = lane & 15;

  if (by < 2) {             // ---- chunkstate: Sb[g][d][m] bf16 ----
    const int m0 = bx * 128, d0 = by * 128;
    mfma_tile_gemm(vT + (size_t)g * (D_*C_) + (size_t)d0 * C_, C_,
                   kpT + (size_t)g * (M_*C_) + (size_t)m0 * C_, C_, C_,
                   smem, smem + 8192, acc);
    #pragma unroll
    for (int i = 0; i < 4; ++i) {
      int lr = wm * 64 + i * 16 + q * 4;
      #pragma unroll
      for (int j = 0; j < 4; ++j) {
        int lc = wn * 64 + j * 16 + ln;
        #pragma unroll
        for (int r = 0; r < 4; ++r)
          smem[(size_t)(lr + r) * 136 + lc] = f2b(acc[i][j][r]);
      }
    }
    __syncthreads();
    #pragma unroll
    for (int it = 0; it < 8; ++it) {
      int idx = tid + 256 * it;         // [0,2048)
      int row = idx >> 4, c8 = idx & 15;
      short8 vv = *(const short8*)(smem + (size_t)row * 136 + c8 * 8);
      *(short8*)(Sb + ((size_t)g * D_ + d0 + row) * M_ + m0 + c8 * 8) = vv;
    }
  } else {                  // ---- qk: Am[g][t][t'] masked ----
    const int tt0 = (bx >> 1) * 128, tp0 = (bx & 1) * 128;
    short* Ag = Am + (size_t)g * (C_*C_);
    if (tp0 > tt0) {
      short8 z8 = 0;
      #pragma unroll
      for (int it = 0; it < 8; ++it) {
        int ci = tid + 256 * it;
        int row = ci >> 4, c8 = ci & 15;
        *(short8*)(Ag + (size_t)(tt0 + row) * C_ + tp0 + c8 * 8) = z8;
      }
      return;
    }
    const size_t cb = (size_t)g * C_;
    mfma_tile_gemm(qp + (cb + tt0) * M_, M_, kp + (cb + tp0) * M_, M_, M_,
                   smem, smem + 8192, acc);
    #pragma unroll
    for (int i = 0; i < 4; ++i) {
      int lr = wm * 64 + i * 16 + q * 4;
      #pragma unroll
      for (int j = 0; j < 4; ++j) {
        int lc = wn * 64 + j * 16 + ln;
        #pragma unroll
        for (int r = 0; r < 4; ++r) {
          short bv = ((tp0 + lc) <= (tt0 + lr + r)) ? f2b(acc[i][j][r]) : (short)0;
          smem[(size_t)(lr + r) * 136 + lc] = bv;
        }
      }
    }
    __syncthreads();
    #pragma unroll
    for (int it = 0; it < 8; ++it) {
      int idx = tid + 256 * it;         // [0,2048)
      int row = idx >> 4, c8 = idx & 15;
      short8 vv = *(const short8*)(smem + (size_t)row * 136 + c8 * 8);
      *(short8*)(Ag + (size_t)(tt0 + row) * C_ + tp0 + c8 * 8) = vv;
    }
  }
}

// ---- K4: exclusive chunk prefix of Sb (bf16 in, fp32 accum) -> Pb -------
__global__ __launch_bounds__(256) void prefixS_kernel(
    const short* __restrict__ Sb, short* __restrict__ Pb)
{
  int j = blockIdx.x * 256 + threadIdx.x;   // 65536 vec8 lanes
  int b = j >> 14, e8 = j & 16383;
  size_t base = ((size_t)b * NC_) * 131072 + (size_t)e8 * 8;
  short8 t[NC_];
  #pragma unroll
  for (int i = 0; i < NC_; ++i)
    t[i] = *(const short8*)(Sb + base + (size_t)i * 131072);
  float run[8] = {0.f,0.f,0.f,0.f,0.f,0.f,0.f,0.f};
  #pragma unroll
  for (int i = 0; i < NC_; ++i) {
    short8 o;
    #pragma unroll
    for (int u = 0; u < 8; ++u) { o[u] = f2b(run[u]); run[u] += b2f(t[i][u]); }
    *(short8*)(Pb + base + (size_t)i * 131072) = o;
  }
}

// ---- K5: out = (qp@Pb^T + Am@vT^T) / den, den FUSED ---------------------
// Round-3: both GEMM parts staged via global_load_lds; the fused den now
// reads the staged bf16 back from LDS after the barrier (bit-identical
// values, same summation order as the old register path).
__global__ __launch_bounds__(256) void out_mfma_kernel(
    const short* __restrict__ qp, const short* __restrict__ Pb,
    const short* __restrict__ Am, const short* __restrict__ vT,
    const float* __restrict__ ZP, float* __restrict__ out)
{
  const int id = blockIdx.x + 2 * blockIdx.y + 8 * blockIdx.z;
  const int g  = (id & 7) + 8 * (id >> 6);
  const int inner = (id >> 3) & 7;
  const int d0 = (inner & 1) * 128, tt0 = (inner >> 1) * 64;
  __shared__ short smem[16896];   // sA 4096 | sB 8192 shorts; epi 64x132 f32
  __shared__ float zbuf[512];
  __shared__ float dbuf[64];
  short* sA = smem; short* sB = smem + 4096;
  const int tid = threadIdx.x, lane = tid & 63, wave = tid >> 6;
  const int wm = wave >> 1, wn = wave & 1, q = lane >> 4, ml = lane & 15;
  const int r8 = tid >> 3;

  { // phase 0: exclusive z-prefix for chunk g into LDS (ZP is L2-resident)
    int b = g >> 4, gi = g & 15;
    float s0 = 0.f, s1 = 0.f;
    const float* zp0 = ZP + (size_t)(b * NC_) * 2 * M_;
    for (int i = 0; i < gi; ++i) {
      const float* r = zp0 + (size_t)i * 2 * M_;
      s0 += r[tid] + r[M_ + tid];
      s1 += r[tid + 256] + r[M_ + tid + 256];
    }
    zbuf[tid] = s0; zbuf[tid + 256] = s1;
    if (tid < 64) dbuf[tid] = 0.f;
  }
  __syncthreads();

  // source decode: sA 64x64 (s in [0,512)): M 2 bits, h = s>>8;
  //                sB 128x64 (s in [0,1024)): M 3 bits, h = s>>9.
  int mA[2], kA[2], mB[4], kB[4];
  #pragma unroll
  for (int it = 0; it < 2; ++it) {
    int s = tid + 256 * it;
    int x = s & 15, l = (s >> 4) & 3, M = (s >> 6) & 3, h = s >> 8;
    int k8 = 4 * h + l;
    mA[it] = M * 16 + (x ^ k8); kA[it] = k8 * 8;
  }
  #pragma unroll
  for (int it = 0; it < 4; ++it) {
    int s = tid + 256 * it;
    int x = s & 15, l = (s >> 4) & 3, M = (s >> 6) & 7, h = s >> 9;
    int k8 = 4 * h + l;
    mB[it] = M * 16 + (x ^ k8); kB[it] = k8 * 8;
  }

  floatx4 acc[2][4];
  #pragma unroll
  for (int i = 0; i < 2; ++i)
    #pragma unroll
    for (int j = 0; j < 4; ++j) acc[i][j] = (floatx4){0.f,0.f,0.f,0.f};

  // ---- part 1: qp[64xK] @ Pb[128xK]^T (K=512) + den part 1 ----
  {
    const short* Ag = qp + ((size_t)g * C_ + tt0) * M_;
    const short* Bg = Pb + (size_t)g * (D_*M_) + (size_t)d0 * M_;
    float dp[2] = {0.f, 0.f};
    for (int k0 = 0; k0 < M_; k0 += 64) {
      #pragma unroll
      for (int it = 0; it < 2; ++it)
        async_copy16(Ag + (size_t)mA[it] * M_ + k0 + kA[it], sA + (tid + 256 * it) * 8);
      #pragma unroll
      for (int it = 0; it < 4; ++it)
        async_copy16(Bg + (size_t)mB[it] * M_ + k0 + kB[it], sB + (tid + 256 * it) * 8);
      __syncthreads();
      // den part 1: read the staged qp back from LDS (swizzled slot)
      #pragma unroll
      for (int it = 0; it < 2; ++it) {
        int ci = tid + 256 * it;
        int m = ci >> 3, k8 = ci & 7;
        int dst = (k8 >> 2) * 256 + (m >> 4) * 64 + (k8 & 3) * 16 + ((m & 15) ^ k8);
        short8 pa = *(const short8*)(sA + dst * 8);
        const float* zz = zbuf + k0 + k8 * 8;
        float d = 0.f;
        #pragma unroll
        for (int u = 0; u < 8; ++u) d = fmaf(b2f(pa[u]), zz[u], d);
        dp[it] += d;
      }
      #pragma unroll
      for (int ks = 0; ks < 2; ++ks) {
        short8 a[2], b[4];
        int k8 = ks * 4 + q;
        #pragma unroll
        for (int i = 0; i < 2; ++i) {
          int ca = ks * 256 + (wm * 2 + i) * 64 + q * 16 + (ml ^ k8);
          a[i] = *(const short8*)(sA + ca * 8);
        }
        #pragma unroll
        for (int j = 0; j < 4; ++j) {
          int cb = ks * 512 + (wn * 4 + j) * 64 + q * 16 + (ml ^ k8);
          b[j] = *(const short8*)(sB + cb * 8);
        }
        #pragma unroll
        for (int i = 0; i < 2; ++i)
          #pragma unroll
          for (int j = 0; j < 4; ++j)
            acc[i][j] = __builtin_amdgcn_mfma_f32_16x16x32_bf16(a[i], b[j], acc[i][j], 0, 0, 0);
      }
      __syncthreads();
    }
    #pragma unroll
    for (int o = 1; o < 8; o <<= 1)
      #pragma unroll
      for (int it = 0; it < 2; ++it) dp[it] += __shfl_xor(dp[it], o);
    if ((tid & 7) == 0) {
      #pragma unroll
      for (int it = 0; it < 2; ++it) dbuf[r8 + 32 * it] += dp[it];
    }
  }

  // ---- part 2: Am[64xK] @ vT[128xK]^T (K=256) + den part 2 (rowsum) ----
  {
    const short* Ag = Am + ((size_t)g * C_ + tt0) * C_;
    const short* Bg = vT + (size_t)g * (D_*C_) + (size_t)d0 * C_;
    float dp[2] = {0.f, 0.f};
    for (int k0 = 0; k0 < C_; k0 += 64) {
      #pragma unroll
      for (int it = 0; it < 2; ++it)
        async_copy16(Ag + (size_t)mA[it] * C_ + k0 + kA[it], sA + (tid + 256 * it) * 8);
      #pragma unroll
      for (int it = 0; it < 4; ++it)
        async_copy16(Bg + (size_t)mB[it] * C_ + k0 + kB[it], sB + (tid + 256 * it) * 8);
      __syncthreads();
      // den part 2: rowsum of Am read back from LDS
      #pragma unroll
      for (int it = 0; it < 2; ++it) {
        int ci = tid + 256 * it;
        int m = ci >> 3, k8 = ci & 7;
        int dst = (k8 >> 2) * 256 + (m >> 4) * 64 + (k8 & 3) * 16 + ((m & 15) ^ k8);
        short8 pa = *(const short8*)(sA + dst * 8);
        float d = 0.f;
        #pragma unroll
        for (int u = 0; u < 8; ++u) d += b2f(pa[u]);
        dp[it] += d;
      }
      #pragma unroll
      for (int ks = 0; ks < 2; ++ks) {
        short8 a[2], b[4];
        int k8 = ks * 4 + q;
        #pragma unroll
        for (int i = 0; i < 2; ++i) {
          int ca = ks * 256 + (wm * 2 + i) * 64 + q * 16 + (ml ^ k8);
          a[i] = *(const short8*)(sA + ca * 8);
        }
        #pragma unroll
        for (int j = 0; j < 4; ++j) {
          int cb = ks * 512 + (wn * 4 + j) * 64 + q * 16 + (ml ^ k8);
          b[j] = *(const short8*)(sB + cb * 8);
        }
        #pragma unroll
        for (int i = 0; i < 2; ++i)
          #pragma unroll
          for (int j = 0; j < 4; ++j)
            acc[i][j] = __builtin_amdgcn_mfma_f32_16x16x32_bf16(a[i], b[j], acc[i][j], 0, 0, 0);
      }
      __syncthreads();
    }
    #pragma unroll
    for (int o = 1; o < 8; o <<= 1)
      #pragma unroll
      for (int it = 0; it < 2; ++it) dp[it] += __shfl_xor(dp[it], o);
    if ((tid & 7) == 0) {
      #pragma unroll
      for (int it = 0; it < 2; ++it) dbuf[r8 + 32 * it] += dp[it];
    }
  }
  __syncthreads();   // dbuf complete

  // ---- epilogue: divide by fused den, stage fp32 in LDS, float4 store ----
  float* smF = (float*)smem;   // [64][132]
  #pragma unroll
  for (int i = 0; i < 2; ++i) {
    int lr = wm * 32 + i * 16 + q * 4;
    #pragma unroll
    for (int r = 0; r < 4; ++r) {
      float rc = 1.0f / (dbuf[lr + r] + EPS_);
      #pragma unroll
      for (int j = 0; j < 4; ++j) {
        int lc = wn * 64 + j * 16 + ml;
        smF[(size_t)(lr + r) * 132 + lc] = acc[i][j][r] * rc;
      }
    }
  }
  __syncthreads();
  #pragma unroll
  for (int it = 0; it < 8; ++it) {
    int idx = tid + 256 * it;           // [0,2048)
    int row = idx >> 5, c4 = idx & 31;
    float4 val = *(const float4*)(smF + (size_t)row * 132 + c4 * 4);
    *(float4*)(out + (size_t)(g * C_ + tt0 + row) * D_ + d0 + c4 * 4) = val;
  }
}

// ---- host-side launch ---------------------------------------------------
extern "C" void kernel_launch(void* const* d_in, const int* in_sizes, int n_in,
                              void* d_out, int out_size, void* d_ws, size_t ws_size,
                              hipStream_t stream) {
  const float* q = (const float*)d_in[0];
  const float* k = (const float*)d_in[1];
  const float* v = (const float*)d_in[2];
  const float* W = (const float*)d_in[3];
  float* out = (float*)d_out;
  char* ws = (char*)d_ws;

  short* Sb  = (short*)(ws + OFF_SB);
  short* Wt  = (short*)(ws + OFF_WT);
  short* qp  = (short*)(ws + OFF_QP);
  short* kp  = (short*)(ws + OFF_KP);
  short* kpT = (short*)(ws + OFF_KPT);
  short* vT  = (short*)(ws + OFF_VT);
  short* Am  = (short*)(ws + OFF_AM);
  short* Pb  = (short*)(ws + OFF_PB);
  float* ZP  = (float*)(ws + OFF_ZP);

  // v [g][t][d] -> vT [g][d][t]  (z<64)  and  W [k][n] -> Wt [n][k] (z==64)
  transpose_cvt_kernel<<<dim3(8, 4, NG_ + 1), 256, 0, stream>>>(v, W, vT, Wt);
  // q-phi (z=0) and k-phi (z=1, also emits kpT and ZP column sums)
  phi_mfma_kernel<<<dim3(2, 128, 2), 512, 0, stream>>>(q, k, Wt, qp, kp, kpT, ZP);
  // chunkstate + qk (zsum lives in K2)
  mega_kernel<<<dim3(4, 3, NG_), 256, 0, stream>>>(vT, kpT, qp, kp, Sb, Am);
  prefixS_kernel<<<(B_*D_*M_)/2048, 256, 0, stream>>>(Sb, Pb);
  // out with fused z-prefix + den, 64x128 tiles (512 blocks)
  out_mfma_kernel<<<dim3(2, 4, NG_), 256, 0, stream>>>(qp, Pb, Am, vT, ZP, out);
}

// Round 5
// 156.455 us; speedup vs baseline: 1.1223x; 1.1223x over previous
//
#include <hip/hip_runtime.h>

// ---- problem constants --------------------------------------------------
#define B_ 4
#define L_ 4096
#define D_ 256
#define M_ 512
#define C_ 256
#define NC_ 16
#define NG_ (B_*NC_)
#define EPS_ 1e-6f
#define RSQRT_D_ 0.0625f
#define RSQRT_M_ 0.044194173824159216f

typedef __attribute__((ext_vector_type(8))) short short8;
typedef __attribute__((ext_vector_type(4))) short short4v;
typedef __attribute__((ext_vector_type(4))) float floatx4;

// ---- bf16 helpers (RNE) -------------------------------------------------
__device__ __forceinline__ short f2b(float f) {
  union { float f; unsigned u; } c; c.f = f;
  unsigned r = c.u + 0x7fffu + ((c.u >> 16) & 1u);
  return (short)(r >> 16);
}
__device__ __forceinline__ float b2f(short s) {
  union { unsigned u; float f; } c; c.u = ((unsigned)(unsigned short)s) << 16;
  return c.f;
}

// async global->LDS, 16B per lane. LDS dest = wave-uniform base + lane*16;
// global source must stay COALESCED (round-3 lesson: swizzling the source
// row index turns the staging into a gather -- 19us regression).
__device__ __forceinline__ void async_copy16(const short* g, short* l) {
  __builtin_amdgcn_global_load_lds(
      (const __attribute__((address_space(1))) void*)(g),
      (__attribute__((address_space(3))) void*)(l), 16, 0, 0);
}

// ---- workspace layout (byte offsets) ------------------------------------
#define OFF_SB   0u
#define OFF_WT   16777216u
#define OFF_QP   17039360u
#define OFF_KP   33816576u
#define OFF_KPT  50593792u
#define OFF_VT   67371008u
#define OFF_AM   75759616u
#define OFF_PB   84148224u
#define OFF_ZP   100925440u
// ZPX (exclusive z-prefix, fp32 [64][512] = 128KB) reuses the Wt slot:
// Wt is dead after phi_mfma, ZPX is written by prefixS and read by out.

// ======================================================================
// MFMA GEMM core, round-4: m97-exact global_load_lds staging.
// LINEAR LDS [128 rows][64 k] per operand; linear coalesced source
// (row = s>>3, k8 = s&7: each 8-lane group reads one contiguous 128B run).
// ds_read fragments take the 16-way bank conflict (m97/m98: measured
// acceptable; m151: this config 874 TF vs reg-staged 646 at same tile).
// ======================================================================
__device__ __forceinline__ void mfma_tile_gemm(
    const short* __restrict__ Ag, int lda,
    const short* __restrict__ Bg, int ldb,
    int K, short* sA, short* sB, floatx4 acc[4][4])
{
  const int tid  = threadIdx.x;
  const int lane = tid & 63;
  const int wave = tid >> 6;
  const int wm = wave >> 1, wn = wave & 1;
  const int q = lane >> 4, ml = lane & 15;

  for (int k0 = 0; k0 < K; k0 += 64) {
    #pragma unroll
    for (int it = 0; it < 4; ++it) {
      int s = tid + 256 * it;
      int m = s >> 3, k8 = s & 7;
      async_copy16(Ag + (size_t)m * lda + k0 + k8 * 8, sA + s * 8);
      async_copy16(Bg + (size_t)m * ldb + k0 + k8 * 8, sB + s * 8);
    }
    __syncthreads();   // compiler drains vmcnt(0) before s_barrier
    #pragma unroll
    for (int ks = 0; ks < 2; ++ks) {
      short8 a[4], b[4];
      int k8 = ks * 4 + q;
      #pragma unroll
      for (int i = 0; i < 4; ++i) {
        int ra = wm * 64 + i * 16 + ml;          // A row
        a[i] = *(const short8*)(sA + (ra * 8 + k8) * 8);
        int rb = wn * 64 + i * 16 + ml;          // B row
        b[i] = *(const short8*)(sB + (rb * 8 + k8) * 8);
      }
      #pragma unroll
      for (int i = 0; i < 4; ++i)
        #pragma unroll
        for (int j = 0; j < 4; ++j)
          acc[i][j] = __builtin_amdgcn_mfma_f32_16x16x32_bf16(a[i], b[j], acc[i][j], 0, 0, 0);
    }
    __syncthreads();
  }
}

// ---- K1: combined transpose+cvt: v (z<NG_) and W (z==NG_) ---------------
__global__ __launch_bounds__(256) void transpose_cvt_kernel(
    const float* __restrict__ v, const float* __restrict__ W,
    short* __restrict__ vT, short* __restrict__ Wt)
{
  const int z = blockIdx.z;
  const float* src; short* dst; int ld_in, ld_out;
  if (z < NG_) {
    if (blockIdx.x >= 4) return;
    src = v + (size_t)z * (C_*D_) + (size_t)blockIdx.y * 64 * D_ + blockIdx.x * 64;
    dst = vT + (size_t)z * (D_*C_) + (size_t)blockIdx.x * 64 * C_ + blockIdx.y * 64;
    ld_in = D_; ld_out = C_;
  } else {
    src = W + (size_t)blockIdx.y * 64 * M_ + blockIdx.x * 64;
    dst = Wt + (size_t)blockIdx.x * 64 * D_ + blockIdx.y * 64;
    ld_in = M_; ld_out = D_;
  }
  __shared__ short sm[64 * 65];
  const int tid = threadIdx.x;
  #pragma unroll
  for (int it = 0; it < 4; ++it) {
    int ci = tid + 256 * it;
    int row = ci >> 4, c4 = ci & 15;
    float4 x = *(const float4*)(src + (size_t)row * ld_in + c4 * 4);
    sm[(c4 * 4 + 0) * 65 + row] = f2b(x.x);
    sm[(c4 * 4 + 1) * 65 + row] = f2b(x.y);
    sm[(c4 * 4 + 2) * 65 + row] = f2b(x.z);
    sm[(c4 * 4 + 3) * 65 + row] = f2b(x.w);
  }
  __syncthreads();
  #pragma unroll
  for (int it = 0; it < 2; ++it) {
    int ci = tid + 256 * it;
    int dr = ci >> 3, t8 = ci & 7;
    short8 o;
    #pragma unroll
    for (int u = 0; u < 8; ++u) o[u] = sm[dr * 65 + t8 * 8 + u];
    *(short8*)(dst + (size_t)dr * ld_out + t8 * 8) = o;
  }
}

// ---- K2: merged q/k phi = exp(X@W/sqrt(d) - 0.5||x||^2)/sqrt(M) ---------
// 128 rows x 256 cols per block, 512 threads (8 waves 2x4). Round-2 form
// (reg-staged, swizzled LDS): kept as the isolation control this round.
__global__ __launch_bounds__(512) void phi_mfma_kernel(
    const float* __restrict__ qin, const float* __restrict__ kin,
    const short* __restrict__ Wt,
    short* __restrict__ qp, short* __restrict__ kp, short* __restrict__ kpT,
    float* __restrict__ ZP)
{
  const bool is_k = (blockIdx.z == 1);
  const float* X = is_k ? kin : qin;
  short* outP = is_k ? kp : qp;
  // XCD-affine: the 2 col-tiles sharing X rows get the same (id mod 8).
  const int idl = blockIdx.x + 2 * blockIdx.y;          // [0,256)
  const int row0 = ((idl & 7) + 8 * (idl >> 4)) * 128;  // [0,16384)
  const int col0 = ((idl >> 3) & 1) * 256;              // {0,256}
  __shared__ short smem[34816];
  __shared__ float zsb[512];
  __shared__ float sqs[128];
  short* sA = smem;
  short* sB = smem + 8192;
  const int tid = threadIdx.x, lane = tid & 63, wave = tid >> 6;
  const int wm = wave >> 2, wn = wave & 3, q = lane >> 4, ml = lane & 15;
  const int c8 = tid & 7, r8 = tid >> 3;   // r8 in [0,64)
  floatx4 acc[4][4];
  #pragma unroll
  for (int i = 0; i < 4; ++i)
    #pragma unroll
    for (int j = 0; j < 4; ++j) acc[i][j] = (floatx4){0.f,0.f,0.f,0.f};

  // X prefetch: thread covers rows r8 and r8+64, k-cols [c8*8, c8*8+8)
  float4 px0[2], px1[2];
  #pragma unroll
  for (int it = 0; it < 2; ++it) {
    const float* src = X + (size_t)(row0 + r8 + 64 * it) * D_ + c8 * 8;
    px0[it] = *(const float4*)src;
    px1[it] = *(const float4*)(src + 4);
  }
  float ssq[2] = {0.f, 0.f};
  for (int k0 = 0; k0 < D_; k0 += 64) {
    // stage X (f2b + ssq) into sA: 128 rows x 64
    #pragma unroll
    for (int it = 0; it < 2; ++it) {
      int m = r8 + 64 * it;
      float4 x0 = px0[it], x1 = px1[it];
      short8 vv;
      vv[0] = f2b(x0.x); vv[1] = f2b(x0.y); vv[2] = f2b(x0.z); vv[3] = f2b(x0.w);
      vv[4] = f2b(x1.x); vv[5] = f2b(x1.y); vv[6] = f2b(x1.z); vv[7] = f2b(x1.w);
      ssq[it] += x0.x*x0.x + x0.y*x0.y + x0.z*x0.z + x0.w*x0.w
               + x1.x*x1.x + x1.y*x1.y + x1.z*x1.z + x1.w*x1.w;
      *(short8*)(sA + (c8 * 128 + (m ^ c8)) * 8) = vv;
    }
    // stage Wt into sB: 256 cols x 64 (L2-resident)
    #pragma unroll
    for (int it = 0; it < 4; ++it) {
      int mm = r8 + 64 * it;
      short8 wb = *(const short8*)(Wt + (size_t)(col0 + mm) * D_ + k0 + c8 * 8);
      *(short8*)(sB + (c8 * 256 + (mm ^ c8)) * 8) = wb;
    }
    if (k0 + 64 < D_) {     // prefetch next X slice before the barrier
      #pragma unroll
      for (int it = 0; it < 2; ++it) {
        const float* src = X + (size_t)(row0 + r8 + 64 * it) * D_ + k0 + 64 + c8 * 8;
        px0[it] = *(const float4*)src;
        px1[it] = *(const float4*)(src + 4);
      }
    }
    __syncthreads();
    #pragma unroll
    for (int ks = 0; ks < 2; ++ks) {
      short8 a[4], b[4];
      int kk = ks * 4 + q;
      #pragma unroll
      for (int i = 0; i < 4; ++i) {
        int ra = (wm * 64 + i * 16 + ml) ^ kk;
        a[i] = *(const short8*)(sA + (kk * 128 + ra) * 8);
        int rb = (wn * 64 + i * 16 + ml) ^ kk;
        b[i] = *(const short8*)(sB + (kk * 256 + rb) * 8);
      }
      #pragma unroll
      for (int i = 0; i < 4; ++i)
        #pragma unroll
        for (int j = 0; j < 4; ++j)
          acc[i][j] = __builtin_amdgcn_mfma_f32_16x16x32_bf16(a[i], b[j], acc[i][j], 0, 0, 0);
    }
    __syncthreads();
  }
  // reduce ssq across the 8 threads sharing r8 (consecutive lanes)
  #pragma unroll
  for (int o = 1; o < 8; o <<= 1)
    #pragma unroll
    for (int it = 0; it < 2; ++it) ssq[it] += __shfl_xor(ssq[it], o);
  if (c8 == 0) {
    sqs[r8] = 0.5f * ssq[0];
    sqs[r8 + 64] = 0.5f * ssq[1];
  }
  __syncthreads();

  if (!is_k) {
    // ---- q epilogue: exp -> row-major LDS [128][264] -> short8 stores ----
    #pragma unroll
    for (int i = 0; i < 4; ++i) {
      int rl = wm * 64 + i * 16 + q * 4;
      float sqv[4];
      #pragma unroll
      for (int r = 0; r < 4; ++r) sqv[r] = sqs[rl + r];
      #pragma unroll
      for (int j = 0; j < 4; ++j) {
        int cl = wn * 64 + j * 16 + ml;   // [0,256)
        #pragma unroll
        for (int r = 0; r < 4; ++r) {
          float pv = __expf(fmaf(acc[i][j][r], RSQRT_D_, -sqv[r])) * RSQRT_M_;
          smem[(size_t)(rl + r) * 264 + cl] = f2b(pv);
        }
      }
    }
    __syncthreads();
    #pragma unroll
    for (int it = 0; it < 8; ++it) {
      int idx = tid + 512 * it;          // [0,4096)
      int row = idx >> 5, cc8 = idx & 31;
      short8 vv = *(const short8*)(smem + (size_t)row * 264 + cc8 * 8);
      *(short8*)(outP + (size_t)(row0 + row) * M_ + col0 + cc8 * 8) = vv;
    }
  } else {
    // ---- k epilogue: kp store + transpose buffer + zsum ----
    float csum[4] = {0.f, 0.f, 0.f, 0.f};
    #pragma unroll
    for (int i = 0; i < 4; ++i) {
      int rl = wm * 64 + i * 16 + q * 4;
      float sqv[4];
      #pragma unroll
      for (int r = 0; r < 4; ++r) sqv[r] = sqs[rl + r];
      #pragma unroll
      for (int j = 0; j < 4; ++j) {
        int cl = wn * 64 + j * 16 + ml;   // [0,256)
        short4v tb;
        #pragma unroll
        for (int r = 0; r < 4; ++r) {
          float pv = __expf(fmaf(acc[i][j][r], RSQRT_D_, -sqv[r])) * RSQRT_M_;
          short bv = f2b(pv);
          outP[(size_t)(row0 + rl + r) * M_ + col0 + cl] = bv;
          tb[r] = bv;
          csum[j] += b2f(bv);   // matches old zsum: sums the ROUNDED kp
        }
        *(short4v*)(smem + (size_t)cl * 136 + rl) = tb;
      }
    }
    // column sums: reduce over q (lanes ml, ml+16, ml+32, ml+48)
    #pragma unroll
    for (int j = 0; j < 4; ++j) {
      csum[j] += __shfl_xor(csum[j], 16);
      csum[j] += __shfl_xor(csum[j], 32);
    }
    if (lane < 16) {
      #pragma unroll
      for (int j = 0; j < 4; ++j)
        zsb[wm * 256 + wn * 64 + j * 16 + ml] = csum[j];
    }
    __syncthreads();
    int g = row0 >> 8, tb0 = row0 & 255;
    #pragma unroll
    for (int it = 0; it < 8; ++it) {
      int ci = tid + 512 * it;          // [0,4096)
      int t8 = ci & 15, cc = ci >> 4;   // cc in [0,256)
      short8 vv = *(const short8*)(smem + (size_t)cc * 136 + t8 * 8);
      *(short8*)(kpT + (size_t)g * (M_*C_) + (size_t)(col0 + cc) * C_ + tb0 + t8 * 8) = vv;
    }
    if (tid < 256) {
      float s = zsb[tid] + zsb[256 + tid];
      int p = (row0 >> 7) & 1;
      ZP[((size_t)g * 2 + p) * M_ + col0 + tid] = s;
    }
  }
}

// ---- K3: mega kernel: chunkstate (by<2) + qk (by==2) --------------------
// Round-4: GEMM core switched to m97-style gload_lds (see mfma_tile_gemm).
// Epilogues stay round-2 (LDS-staged short8 stores).
__global__ __launch_bounds__(256) void mega_kernel(
    const short* __restrict__ vT, const short* __restrict__ kpT,
    const short* __restrict__ qp, const short* __restrict__ kp,
    short* __restrict__ Sb, short* __restrict__ Am)
{
  const int id = blockIdx.x + 4 * blockIdx.y + 12 * blockIdx.z;
  const int t12 = id >> 3;
  const int g  = (id & 7) + 8 * (t12 / 12);
  const int inner = t12 % 12;
  const int bx = inner & 3, by = inner >> 2;
  __shared__ short smem[17408];   // gemm uses 16K shorts; epi uses 128x136
  const int tid = threadIdx.x;

  floatx4 acc[4][4];
  #pragma unroll
  for (int i = 0; i < 4; ++i)
    #pragma unroll
    for (int j = 0; j < 4; ++j) acc[i][j] = (floatx4){0.f,0.f,0.f,0.f};
  const int lane = tid & 63, wave = tid >> 6;
  const int wm = wave >> 1, wn = wave & 1, q = lane >> 4, ln = lane & 15;

  if (by < 2) {             // ---- chunkstate: Sb[g][d][m] bf16 ----
    const int m0 = bx * 128, d0 = by * 128;
    mfma_tile_gemm(vT + (size_t)g * (D_*C_) + (size_t)d0 * C_, C_,
                   kpT + (size_t)g * (M_*C_) + (size_t)m0 * C_, C_, C_,
                   smem, smem + 8192, acc);
    #pragma unroll
    for (int i = 0; i < 4; ++i) {
      int lr = wm * 64 + i * 16 + q * 4;
      #pragma unroll
      for (int j = 0; j < 4; ++j) {
        int lc = wn * 64 + j * 16 + ln;
        #pragma unroll
        for (int r = 0; r < 4; ++r)
          smem[(size_t)(lr + r) * 136 + lc] = f2b(acc[i][j][r]);
      }
    }
    __syncthreads();
    #pragma unroll
    for (int it = 0; it < 8; ++it) {
      int idx = tid + 256 * it;         // [0,2048)
      int row = idx >> 4, c8 = idx & 15;
      short8 vv = *(const short8*)(smem + (size_t)row * 136 + c8 * 8);
      *(short8*)(Sb + ((size_t)g * D_ + d0 + row) * M_ + m0 + c8 * 8) = vv;
    }
  } else {                  // ---- qk: Am[g][t][t'] masked ----
    const int tt0 = (bx >> 1) * 128, tp0 = (bx & 1) * 128;
    short* Ag = Am + (size_t)g * (C_*C_);
    if (tp0 > tt0) {
      short8 z8 = 0;
      #pragma unroll
      for (int it = 0; it < 8; ++it) {
        int ci = tid + 256 * it;
        int row = ci >> 4, c8 = ci & 15;
        *(short8*)(Ag + (size_t)(tt0 + row) * C_ + tp0 + c8 * 8) = z8;
      }
      return;
    }
    const size_t cb = (size_t)g * C_;
    mfma_tile_gemm(qp + (cb + tt0) * M_, M_, kp + (cb + tp0) * M_, M_, M_,
                   smem, smem + 8192, acc);
    #pragma unroll
    for (int i = 0; i < 4; ++i) {
      int lr = wm * 64 + i * 16 + q * 4;
      #pragma unroll
      for (int j = 0; j < 4; ++j) {
        int lc = wn * 64 + j * 16 + ln;
        #pragma unroll
        for (int r = 0; r < 4; ++r) {
          short bv = ((tp0 + lc) <= (tt0 + lr + r)) ? f2b(acc[i][j][r]) : (short)0;
          smem[(size_t)(lr + r) * 136 + lc] = bv;
        }
      }
    }
    __syncthreads();
    #pragma unroll
    for (int it = 0; it < 8; ++it) {
      int idx = tid + 256 * it;         // [0,2048)
      int row = idx >> 4, c8 = idx & 15;
      short8 vv = *(const short8*)(smem + (size_t)row * 136 + c8 * 8);
      *(short8*)(Ag + (size_t)(tt0 + row) * C_ + tp0 + c8 * 8) = vv;
    }
  }
}

// ---- K4: exclusive chunk prefix of Sb -> Pb; blocks >=256 also build ----
// ZPX[g][m] = exclusive prefix of the per-chunk z column sums (removes
// K5's serial phase-0 loop whose g=15 stragglers gated the kernel).
__global__ __launch_bounds__(256) void prefixS_kernel(
    const short* __restrict__ Sb, short* __restrict__ Pb,
    const float* __restrict__ ZP, float* __restrict__ ZPX)
{
  if (blockIdx.x >= 256) {
    int idx = (blockIdx.x - 256) * 256 + threadIdx.x;   // [0,2048)
    int b = idx >> 9, m = idx & 511;
    float run = 0.f;
    #pragma unroll
    for (int i = 0; i < NC_; ++i) {
      int g = b * NC_ + i;
      ZPX[(size_t)g * M_ + m] = run;
      // same order as old K5 phase-0: r[tid] + r[M_+tid] per chunk
      run += ZP[((size_t)g * 2 + 0) * M_ + m] + ZP[((size_t)g * 2 + 1) * M_ + m];
    }
    return;
  }
  int j = blockIdx.x * 256 + threadIdx.x;   // 65536 vec8 lanes
  int b = j >> 14, e8 = j & 16383;
  size_t base = ((size_t)b * NC_) * 131072 + (size_t)e8 * 8;
  short8 t[NC_];
  #pragma unroll
  for (int i = 0; i < NC_; ++i)
    t[i] = *(const short8*)(Sb + base + (size_t)i * 131072);
  float run[8] = {0.f,0.f,0.f,0.f,0.f,0.f,0.f,0.f};
  #pragma unroll
  for (int i = 0; i < NC_; ++i) {
    short8 o;
    #pragma unroll
    for (int u = 0; u < 8; ++u) { o[u] = f2b(run[u]); run[u] += b2f(t[i][u]); }
    *(short8*)(Pb + base + (size_t)i * 131072) = o;
  }
}

// ---- K5: out = (qp@Pb^T + Am@vT^T) / den, den FUSED ---------------------
// Round-2 GEMM form (reg-staged, swizzled -- isolation control).
// Round-4: phase 0 reads precomputed ZPX (2 loads, was up to 15 L2 trips).
__global__ __launch_bounds__(256) void out_mfma_kernel(
    const short* __restrict__ qp, const short* __restrict__ Pb,
    const short* __restrict__ Am, const short* __restrict__ vT,
    const float* __restrict__ ZPX, float* __restrict__ out)
{
  const int id = blockIdx.x + 2 * blockIdx.y + 8 * blockIdx.z;
  const int g  = (id & 7) + 8 * (id >> 6);
  const int inner = (id >> 3) & 7;
  const int d0 = (inner & 1) * 128, tt0 = (inner >> 1) * 64;
  __shared__ short smem[16896];   // sA 4096 | sB 8192 shorts; epi 64x132 f32
  __shared__ float zbuf[512];
  __shared__ float dbuf[64];
  short* sA = smem; short* sB = smem + 4096;
  const int tid = threadIdx.x, lane = tid & 63, wave = tid >> 6;
  const int wm = wave >> 1, wn = wave & 1, q = lane >> 4, ml = lane & 15;
  const int r8 = tid >> 3;

  { // phase 0: z-prefix for chunk g from ZPX (precomputed in K4)
    zbuf[tid]       = ZPX[(size_t)g * M_ + tid];
    zbuf[tid + 256] = ZPX[(size_t)g * M_ + 256 + tid];
    if (tid < 64) dbuf[tid] = 0.f;
  }
  __syncthreads();

  floatx4 acc[2][4];
  #pragma unroll
  for (int i = 0; i < 2; ++i)
    #pragma unroll
    for (int j = 0; j < 4; ++j) acc[i][j] = (floatx4){0.f,0.f,0.f,0.f};

  // ---- part 1: qp[64xK] @ Pb[128xK]^T (K=512) + den part 1 ----
  {
    const short* Ag = qp + ((size_t)g * C_ + tt0) * M_;
    const short* Bg = Pb + (size_t)g * (D_*M_) + (size_t)d0 * M_;
    float dp[2] = {0.f, 0.f};
    short8 pa[2], pb[4];
    #pragma unroll
    for (int it = 0; it < 2; ++it) {
      int ci = tid + 256 * it;
      int m = ci >> 3, k8 = ci & 7;
      pa[it] = *(const short8*)(Ag + (size_t)m * M_ + k8 * 8);
    }
    #pragma unroll
    for (int it = 0; it < 4; ++it) {
      int ci = tid + 256 * it;
      int m = ci >> 3, k8 = ci & 7;
      pb[it] = *(const short8*)(Bg + (size_t)m * M_ + k8 * 8);
    }
    for (int k0 = 0; k0 < M_; k0 += 64) {
      #pragma unroll
      for (int it = 0; it < 2; ++it) {
        int ci = tid + 256 * it;
        int m = ci >> 3, k8 = ci & 7;
        int dst = (k8 >> 2) * 256 + (m >> 4) * 64 + (k8 & 3) * 16 + ((m & 15) ^ k8);
        *(short8*)(sA + dst * 8) = pa[it];
        const float* zz = zbuf + k0 + k8 * 8;
        float d = 0.f;
        #pragma unroll
        for (int u = 0; u < 8; ++u) d = fmaf(b2f(pa[it][u]), zz[u], d);
        dp[it] += d;
      }
      #pragma unroll
      for (int it = 0; it < 4; ++it) {
        int ci = tid + 256 * it;
        int m = ci >> 3, k8 = ci & 7;
        int dst = (k8 >> 2) * 512 + (m >> 4) * 64 + (k8 & 3) * 16 + ((m & 15) ^ k8);
        *(short8*)(sB + dst * 8) = pb[it];
      }
      if (k0 + 64 < M_) {
        #pragma unroll
        for (int it = 0; it < 2; ++it) {
          int ci = tid + 256 * it;
          int m = ci >> 3, k8 = ci & 7;
          pa[it] = *(const short8*)(Ag + (size_t)m * M_ + k0 + 64 + k8 * 8);
        }
        #pragma unroll
        for (int it = 0; it < 4; ++it) {
          int ci = tid + 256 * it;
          int m = ci >> 3, k8 = ci & 7;
          pb[it] = *(const short8*)(Bg + (size_t)m * M_ + k0 + 64 + k8 * 8);
        }
      }
      __syncthreads();
      #pragma unroll
      for (int ks = 0; ks < 2; ++ks) {
        short8 a[2], b[4];
        int k8 = ks * 4 + q;
        #pragma unroll
        for (int i = 0; i < 2; ++i) {
          int ca = ks * 256 + (wm * 2 + i) * 64 + q * 16 + (ml ^ k8);
          a[i] = *(const short8*)(sA + ca * 8);
        }
        #pragma unroll
        for (int j = 0; j < 4; ++j) {
          int cb = ks * 512 + (wn * 4 + j) * 64 + q * 16 + (ml ^ k8);
          b[j] = *(const short8*)(sB + cb * 8);
        }
        #pragma unroll
        for (int i = 0; i < 2; ++i)
          #pragma unroll
          for (int j = 0; j < 4; ++j)
            acc[i][j] = __builtin_amdgcn_mfma_f32_16x16x32_bf16(a[i], b[j], acc[i][j], 0, 0, 0);
      }
      __syncthreads();
    }
    #pragma unroll
    for (int o = 1; o < 8; o <<= 1)
      #pragma unroll
      for (int it = 0; it < 2; ++it) dp[it] += __shfl_xor(dp[it], o);
    if ((tid & 7) == 0) {
      #pragma unroll
      for (int it = 0; it < 2; ++it) dbuf[r8 + 32 * it] += dp[it];
    }
  }

  // ---- part 2: Am[64xK] @ vT[128xK]^T (K=256) + den part 2 (rowsum) ----
  {
    const short* Ag = Am + ((size_t)g * C_ + tt0) * C_;
    const short* Bg = vT + (size_t)g * (D_*C_) + (size_t)d0 * C_;
    float dp[2] = {0.f, 0.f};
    short8 pa[2], pb[4];
    #pragma unroll
    for (int it = 0; it < 2; ++it) {
      int ci = tid + 256 * it;
      int m = ci >> 3, k8 = ci & 7;
      pa[it] = *(const short8*)(Ag + (size_t)m * C_ + k8 * 8);
    }
    #pragma unroll
    for (int it = 0; it < 4; ++it) {
      int ci = tid + 256 * it;
      int m = ci >> 3, k8 = ci & 7;
      pb[it] = *(const short8*)(Bg + (size_t)m * C_ + k8 * 8);
    }
    for (int k0 = 0; k0 < C_; k0 += 64) {
      #pragma unroll
      for (int it = 0; it < 2; ++it) {
        int ci = tid + 256 * it;
        int m = ci >> 3, k8 = ci & 7;
        int dst = (k8 >> 2) * 256 + (m >> 4) * 64 + (k8 & 3) * 16 + ((m & 15) ^ k8);
        *(short8*)(sA + dst * 8) = pa[it];
        float d = 0.f;
        #pragma unroll
        for (int u = 0; u < 8; ++u) d += b2f(pa[it][u]);
        dp[it] += d;
      }
      #pragma unroll
      for (int it = 0; it < 4; ++it) {
        int ci = tid + 256 * it;
        int m = ci >> 3, k8 = ci & 7;
        int dst = (k8 >> 2) * 512 + (m >> 4) * 64 + (k8 & 3) * 16 + ((m & 15) ^ k8);
        *(short8*)(sB + dst * 8) = pb[it];
      }
      if (k0 + 64 < C_) {
        #pragma unroll
        for (int it = 0; it < 2; ++it) {
          int ci = tid + 256 * it;
          int m = ci >> 3, k8 = ci & 7;
          pa[it] = *(const short8*)(Ag + (size_t)m * C_ + k0 + 64 + k8 * 8);
        }
        #pragma unroll
        for (int it = 0; it < 4; ++it) {
          int ci = tid + 256 * it;
          int m = ci >> 3, k8 = ci & 7;
          pb[it] = *(const short8*)(Bg + (size_t)m * C_ + k0 + 64 + k8 * 8);
        }
      }
      __syncthreads();
      #pragma unroll
      for (int ks = 0; ks < 2; ++ks) {
        short8 a[2], b[4];
        int k8 = ks * 4 + q;
        #pragma unroll
        for (int i = 0; i < 2; ++i) {
          int ca = ks * 256 + (wm * 2 + i) * 64 + q * 16 + (ml ^ k8);
          a[i] = *(const short8*)(sA + ca * 8);
        }
        #pragma unroll
        for (int j = 0; j < 4; ++j) {
          int cb = ks * 512 + (wn * 4 + j) * 64 + q * 16 + (ml ^ k8);
          b[j] = *(const short8*)(sB + cb * 8);
        }
        #pragma unroll
        for (int i = 0; i < 2; ++i)
          #pragma unroll
          for (int j = 0; j < 4; ++j)
            acc[i][j] = __builtin_amdgcn_mfma_f32_16x16x32_bf16(a[i], b[j], acc[i][j], 0, 0, 0);
      }
      __syncthreads();
    }
    #pragma unroll
    for (int o = 1; o < 8; o <<= 1)
      #pragma unroll
      for (int it = 0; it < 2; ++it) dp[it] += __shfl_xor(dp[it], o);
    if ((tid & 7) == 0) {
      #pragma unroll
      for (int it = 0; it < 2; ++it) dbuf[r8 + 32 * it] += dp[it];
    }
  }
  __syncthreads();   // dbuf complete

  // ---- epilogue: divide by fused den, stage fp32 in LDS, float4 store ----
  float* smF = (float*)smem;   // [64][132]
  #pragma unroll
  for (int i = 0; i < 2; ++i) {
    int lr = wm * 32 + i * 16 + q * 4;
    #pragma unroll
    for (int r = 0; r < 4; ++r) {
      float rc = 1.0f / (dbuf[lr + r] + EPS_);
      #pragma unroll
      for (int j = 0; j < 4; ++j) {
        int lc = wn * 64 + j * 16 + ml;
        smF[(size_t)(lr + r) * 132 + lc] = acc[i][j][r] * rc;
      }
    }
  }
  __syncthreads();
  #pragma unroll
  for (int it = 0; it < 8; ++it) {
    int idx = tid + 256 * it;           // [0,2048)
    int row = idx >> 5, c4 = idx & 31;
    float4 val = *(const float4*)(smF + (size_t)row * 132 + c4 * 4);
    *(float4*)(out + (size_t)(g * C_ + tt0 + row) * D_ + d0 + c4 * 4) = val;
  }
}

// ---- host-side launch ---------------------------------------------------
extern "C" void kernel_launch(void* const* d_in, const int* in_sizes, int n_in,
                              void* d_out, int out_size, void* d_ws, size_t ws_size,
                              hipStream_t stream) {
  const float* q = (const float*)d_in[0];
  const float* k = (const float*)d_in[1];
  const float* v = (const float*)d_in[2];
  const float* W = (const float*)d_in[3];
  float* out = (float*)d_out;
  char* ws = (char*)d_ws;

  short* Sb  = (short*)(ws + OFF_SB);
  short* Wt  = (short*)(ws + OFF_WT);
  short* qp  = (short*)(ws + OFF_QP);
  short* kp  = (short*)(ws + OFF_KP);
  short* kpT = (short*)(ws + OFF_KPT);
  short* vT  = (short*)(ws + OFF_VT);
  short* Am  = (short*)(ws + OFF_AM);
  short* Pb  = (short*)(ws + OFF_PB);
  float* ZP  = (float*)(ws + OFF_ZP);
  float* ZPX = (float*)(ws + OFF_WT);   // reuse dead Wt slot (128KB needed)

  // v [g][t][d] -> vT [g][d][t]  (z<64)  and  W [k][n] -> Wt [n][k] (z==64)
  transpose_cvt_kernel<<<dim3(8, 4, NG_ + 1), 256, 0, stream>>>(v, W, vT, Wt);
  // q-phi (z=0) and k-phi (z=1, also emits kpT and ZP column sums)
  phi_mfma_kernel<<<dim3(2, 128, 2), 512, 0, stream>>>(q, k, Wt, qp, kp, kpT, ZP);
  // chunkstate + qk (zsum lives in K2)
  mega_kernel<<<dim3(4, 3, NG_), 256, 0, stream>>>(vT, kpT, qp, kp, Sb, Am);
  // prefix of Sb (256 blocks) + z-prefix ZPX (8 blocks)
  prefixS_kernel<<<264, 256, 0, stream>>>(Sb, Pb, ZP, ZPX);
  // out with fused den, 64x128 tiles (512 blocks)
  out_mfma_kernel<<<dim3(2, 4, NG_), 256, 0, stream>>>(qp, Pb, Am, vT, ZPX, out);
}